// Round 1
// baseline (9103.171 us; speedup 1.0000x reference)
//
#include <hip/hip_runtime.h>
#include <stdint.h>

#define BB 64
#define TT 2048
#define EE 256
#define HH 512
#define SLICE 128   // h-rows per block
#define NSLICE 4

typedef unsigned long long u64;

__device__ __forceinline__ u64 pack_vt(float v, unsigned tag) {
    return ((u64)tag << 32) | (u64)__float_as_uint(v);
}

// 256 blocks (4 per batch), 256 threads. Each thread owns:
//   W_hh[row][kh*256 .. +256)  -> 64 float4 in VGPRs
//   W_ih[row][kh*128 .. +128)  -> 32 float4 in VGPRs
// where row = s*128 + w*32 + (lane&31), kh = lane>>5 (2 threads per row).
// Per step: partial dots from LDS-broadcast h/x, shfl_xor(32) reduce, tanh,
// publish slice via tagged u64 agent atomics, gather 3 remote slices.
__global__ __launch_bounds__(256, 1)
void rnn_scan(const float* __restrict__ x,
              const int* __restrict__ lengths,
              const float* __restrict__ W_ih,
              const float* __restrict__ W_hh,
              const float* __restrict__ b_ih,
              const float* __restrict__ b_hh,
              const float* __restrict__ w_fc,
              const float* __restrict__ b_fc,
              float* __restrict__ out,   // [64] counts ++ [64][512] h_n
              u64* __restrict__ hx)      // [B][2][4][128] tagged values
{
    const int b   = blockIdx.x & 63;
    const int s   = blockIdx.x >> 6;
    const int tid = threadIdx.x;
    const int w   = tid >> 6;
    const int l   = tid & 63;
    const int rl  = (w << 5) + (l & 31);   // row within slice, 0..127
    const int row = s * SLICE + rl;        // global h row
    const int kh  = l >> 5;                // 0/1: which half of k/e range

    __shared__ float lds_h[HH];
    __shared__ float lds_x[EE];

    // ---- one-time: weights into registers ----
    float4 whh[64];
#pragma unroll
    for (int i = 0; i < 64; ++i)
        whh[i] = *(const float4*)&W_hh[row * HH + kh * 256 + i * 4];
    float4 wih[32];
#pragma unroll
    for (int i = 0; i < 32; ++i)
        wih[i] = *(const float4*)&W_ih[row * EE + kh * 128 + i * 4];
    const float bsum = b_ih[row] + b_hh[row];

    float4 wf0 = make_float4(0.f, 0.f, 0.f, 0.f), wf1 = wf0;
    float bfc = 0.f;
    if (s == 0 && w == 0) {
        wf0 = *(const float4*)&w_fc[l * 8];
        wf1 = *(const float4*)&w_fc[l * 8 + 4];
        bfc = b_fc[0];
    }

    const int len = lengths[b];
    const float* xrow = x + (size_t)b * TT * EE;

    // init: h0 = 0, stage x[b][0]
    lds_h[tid]       = 0.f;
    lds_h[tid + 256] = 0.f;
    lds_x[tid]       = xrow[tid];
    __syncthreads();

    int count = 0;

#pragma unroll 1
    for (int t = 0; t < len; ++t) {
        // prefetch next x row (1 float/thread, coalesced)
        float xnext = 0.f;
        if (t + 1 < TT) xnext = xrow[(size_t)(t + 1) * EE + tid];

        // ---- partial dot: W_hh slice · h  +  W_ih slice · x ----
        float4 a4 = make_float4(0.f, 0.f, 0.f, 0.f);
        const float4* hp = (const float4*)&lds_h[kh * 256];
#pragma unroll
        for (int i = 0; i < 64; ++i) {
            float4 hv = hp[i];
            a4.x = fmaf(whh[i].x, hv.x, a4.x);
            a4.y = fmaf(whh[i].y, hv.y, a4.y);
            a4.z = fmaf(whh[i].z, hv.z, a4.z);
            a4.w = fmaf(whh[i].w, hv.w, a4.w);
        }
        const float4* xp = (const float4*)&lds_x[kh * 128];
#pragma unroll
        for (int i = 0; i < 32; ++i) {
            float4 xv = xp[i];
            a4.x = fmaf(wih[i].x, xv.x, a4.x);
            a4.y = fmaf(wih[i].y, xv.y, a4.y);
            a4.z = fmaf(wih[i].z, xv.z, a4.z);
            a4.w = fmaf(wih[i].w, xv.w, a4.w);
        }
        float acc = (a4.x + a4.y) + (a4.z + a4.w);
        acc += __shfl_xor(acc, 32);        // combine the two k-halves

        const int p = t & 1;
        u64* slot = hx + (size_t)((b * 2 + p) * NSLICE) * SLICE;
        const unsigned tag = (unsigned)(t + 1);

        float hval = 0.f;
        if ((l & 32) == 0) {
            hval = tanhf(acc + bsum);
            // publish own slice value ASAP (remote readers spin on the tag)
            __hip_atomic_store(&slot[s * SLICE + rl], pack_vt(hval, tag),
                               __ATOMIC_RELAXED, __HIP_MEMORY_SCOPE_AGENT);
        }

        __syncthreads();   // [A] all reads of lds_h/lds_x for step t done

        if ((l & 32) == 0) lds_h[s * SLICE + rl] = hval;
        lds_x[tid] = xnext;

        // ---- gather the 3 remote slices (384 tagged words) ----
        {
            int j   = tid;
            int sp  = (s + 1 + (j >> 7)) & 3;
            int idx = j & 127;
            u64 v; int guard = 0;
            do {
                v = __hip_atomic_load(&slot[sp * SLICE + idx],
                                      __ATOMIC_RELAXED, __HIP_MEMORY_SCOPE_AGENT);
            } while ((unsigned)(v >> 32) != tag && ++guard < (1 << 20));
            lds_h[sp * SLICE + idx] = __uint_as_float((unsigned)v);

            if (tid < 128) {
                j   = tid + 256;
                sp  = (s + 1 + (j >> 7)) & 3;
                idx = j & 127;
                guard = 0;
                do {
                    v = __hip_atomic_load(&slot[sp * SLICE + idx],
                                          __ATOMIC_RELAXED, __HIP_MEMORY_SCOPE_AGENT);
                } while ((unsigned)(v >> 32) != tag && ++guard < (1 << 20));
                lds_h[sp * SLICE + idx] = __uint_as_float((unsigned)v);
            }
        }
        __syncthreads();   // [E] full h_t resident in lds_h

        // ---- fc logit count + h_n capture (block s==0 only) ----
        if (s == 0) {
            if (w == 0) {
                const float4* h4 = (const float4*)lds_h;
                float4 v0 = h4[l * 2], v1 = h4[l * 2 + 1];
                float pd = v0.x * wf0.x + v0.y * wf0.y + v0.z * wf0.z + v0.w * wf0.w
                         + v1.x * wf1.x + v1.y * wf1.y + v1.z * wf1.z + v1.w * wf1.w;
#pragma unroll
                for (int m = 1; m < 64; m <<= 1) pd += __shfl_xor(pd, m);
                if (l == 0 && (pd + bfc) > 0.f) count++;
            }
            if (t == len - 1) {
                out[64 + b * HH + tid * 2]     = lds_h[tid * 2];
                out[64 + b * HH + tid * 2 + 1] = lds_h[tid * 2 + 1];
            }
        }
    }

    if (s == 0 && tid == 0) out[b] = (float)count;
}

extern "C" void kernel_launch(void* const* d_in, const int* in_sizes, int n_in,
                              void* d_out, int out_size, void* d_ws, size_t ws_size,
                              hipStream_t stream) {
    const float* x       = (const float*)d_in[0];
    const int*   lengths = (const int*)  d_in[1];
    const float* W_ih    = (const float*)d_in[2];
    const float* W_hh    = (const float*)d_in[3];
    const float* b_ih    = (const float*)d_in[4];
    const float* b_hh    = (const float*)d_in[5];
    const float* w_fc    = (const float*)d_in[6];
    const float* b_fc    = (const float*)d_in[7];
    float* out = (float*)d_out;
    u64*   hx  = (u64*)d_ws;   // 64*2*4*128*8 = 512 KiB of tagged exchange words

    hipLaunchKernelGGL(rnn_scan, dim3(BB * NSLICE), dim3(256), 0, stream,
                       x, lengths, W_ih, W_hh, b_ih, b_hh, w_fc, b_fc, out, hx);
}